// Round 4
// baseline (494.499 us; speedup 1.0000x reference)
//
#include <hip/hip_runtime.h>

#define N_ENTITIES 500000
#define N_RELS 1000
#define EMB_DIM 128
#define N_TRIPLES 1000000

// ---- segmented-argmax find (replaces device-scope atomics) ----
// K entity segments; SEG entities per segment live in LDS during phase A.
#define K_SEG 32
#define SEG (N_ENTITIES / K_SEG)        // 15625 exact, 61 KB LDS as int

// ---- apply tiling (unchanged from round 2, measured <153 us) ----
#define STEPS 4
#define ROWS_PER_STEP 8
#define BLOCK_ROWS (STEPS * ROWS_PER_STEP) // 32; 500000/32 = 15625 blocks

typedef float floatx4 __attribute__((ext_vector_type(4)));
typedef unsigned long long u64;

// pack[v] encodes the winning triple for entity v, pre-joined:
//   key = (e+1)<<29 | r<<19 | t    (t < 2^19, r < 2^10, e+1 < 2^20); 0 = none.

// Phase A: block (k,m) streams triple-chunk m, keeps argmax(e) for entities in
// segment k in LDS, writes its partial slice. No device-scope atomics.
__global__ void find_seg_kernel(const int* __restrict__ h_idx,
                                int* __restrict__ partial,
                                int M, int CH) {
    __shared__ int lds[SEG];
    int tid = threadIdx.x;
    int k = blockIdx.x & (K_SEG - 1);
    int m = blockIdx.x >> 5;            // K_SEG == 32

    for (int i = tid; i < SEG; i += 256) lds[i] = -1;
    __syncthreads();

    int lo = k * SEG, hi = lo + SEG;
    const int4* h4 = (const int4*)(h_idx + m * CH);
    int quads = CH >> 2;
    for (int q = tid; q < quads; q += 256) {
        int4 h = h4[q];
        int e = m * CH + 4 * q;
        if (h.x >= lo && h.x < hi) atomicMax(&lds[h.x - lo], e);
        if (h.y >= lo && h.y < hi) atomicMax(&lds[h.y - lo], e + 1);
        if (h.z >= lo && h.z < hi) atomicMax(&lds[h.z - lo], e + 2);
        if (h.w >= lo && h.w < hi) atomicMax(&lds[h.w - lo], e + 3);
    }
    __syncthreads();

    int* slice = partial + (size_t)(m * K_SEG + k) * SEG;
    for (int i = tid; i < SEG; i += 256) slice[i] = lds[i];
}

// Phase B: per entity, max over the M chunk partials (coalesced), then join
// r/t (random 4B into L2-resident 4MB tables) and emit the dense pack table.
// Writes every entry -> no init kernel needed.
__global__ void merge_join_kernel(const int* __restrict__ partial,
                                  const int* __restrict__ r_idx,
                                  const int* __restrict__ t_idx,
                                  u64* __restrict__ pack,
                                  int M) {
    int v = blockIdx.x * blockDim.x + threadIdx.x;
    if (v >= N_ENTITIES) return;
    int k = v / SEG, i = v - k * SEG;
    int w = -1;
    for (int m = 0; m < M; ++m) {
        int cand = partial[(size_t)(m * K_SEG + k) * SEG + i];
        w = (cand > w) ? cand : w;
    }
    u64 key = 0ull;
    if (w >= 0) {
        u64 r = (u64)(unsigned)r_idx[w];
        u64 t = (u64)(unsigned)t_idx[w];
        key = ((u64)(w + 1) << 29) | (r << 19) | t;
    }
    pack[v] = key;
}

// ---- fallback path (ws too small): round-2 atomic find ----
__global__ void init_pack_kernel(ulonglong2* __restrict__ pack2, int n2) {
    int i = blockIdx.x * blockDim.x + threadIdx.x;
    if (i < n2) { ulonglong2 z; z.x = 0ull; z.y = 0ull; pack2[i] = z; }
}

__global__ void find_winner_kernel(const int4* __restrict__ h4,
                                   const int4* __restrict__ r4,
                                   const int4* __restrict__ t4,
                                   u64* __restrict__ pack) {
    int q = blockIdx.x * blockDim.x + threadIdx.x;
    if (q >= N_TRIPLES / 4) return;
    int4 h = h4[q]; int4 r = r4[q]; int4 t = t4[q];
    u64 e1 = (u64)(4 * q + 1);
    atomicMax(&pack[h.x], (e1      << 29) | ((u64)r.x << 19) | (u64)t.x);
    atomicMax(&pack[h.y], ((e1 + 1) << 29) | ((u64)r.y << 19) | (u64)t.y);
    atomicMax(&pack[h.z], ((e1 + 2) << 29) | ((u64)r.z << 19) | (u64)t.z);
    atomicMax(&pack[h.w], ((e1 + 3) << 29) | ((u64)r.w << 19) | (u64)t.w);
}

// ---- apply: unchanged structure from round 2 (contiguous 32-row tiles) ----
__global__ void apply_kernel(const float* __restrict__ memory,
                             const float* __restrict__ rel_table,
                             const u64* __restrict__ pack,
                             float* __restrict__ out) {
    int lane = threadIdx.x & 31;
    int hr   = threadIdx.x >> 5;
    int base = blockIdx.x * BLOCK_ROWS;

    int rows[STEPS];
    u64 k[STEPS];
#pragma unroll
    for (int i = 0; i < STEPS; ++i) {
        rows[i] = base + i * ROWS_PER_STEP + hr;
        k[i] = __builtin_nontemporal_load(&pack[rows[i]]);
    }

    floatx4 h[STEPS];
#pragma unroll
    for (int i = 0; i < STEPS; ++i)
        h[i] = ((const floatx4*)(memory + (size_t)rows[i] * EMB_DIM))[lane];

    floatx4 rv[STEPS], tv[STEPS];
#pragma unroll
    for (int i = 0; i < STEPS; ++i) {
        int t = (int)(k[i] & 0x7FFFF);
        int r = (int)((k[i] >> 19) & 0x3FF);
        rv[i] = ((const floatx4*)(rel_table + (size_t)r * EMB_DIM))[lane];
        tv[i] = ((const floatx4*)(memory    + (size_t)t * EMB_DIM))[lane];
    }

#pragma unroll
    for (int i = 0; i < STEPS; ++i) {
        floatx4 upd = 0.9f * h[i] + 0.1f * (h[i] + rv[i] - tv[i]);
        floatx4 val = (k[i] != 0ull) ? upd : h[i];
        floatx4* orow = (floatx4*)(out + (size_t)rows[i] * EMB_DIM) + lane;
        __builtin_nontemporal_store(val, orow);
    }
}

extern "C" void kernel_launch(void* const* d_in, const int* in_sizes, int n_in,
                              void* d_out, int out_size, void* d_ws, size_t ws_size,
                              hipStream_t stream) {
    const float* memory    = (const float*)d_in[0];
    const float* rel_table = (const float*)d_in[1];
    const int*   h_idx     = (const int*)d_in[2];
    const int*   r_idx     = (const int*)d_in[3];
    const int*   t_idx     = (const int*)d_in[4];
    float*       out       = (float*)d_out;

    size_t pack_bytes = (size_t)N_ENTITIES * sizeof(u64);   // 4 MB

    // Pick M (triple chunks) from available workspace: partials M*2MB + pack.
    int M = 0;
    if      (ws_size >= 16 * (size_t)N_ENTITIES * 4 + pack_bytes) M = 16;
    else if (ws_size >=  8 * (size_t)N_ENTITIES * 4 + pack_bytes) M = 8;
    else if (ws_size >=  4 * (size_t)N_ENTITIES * 4 + pack_bytes) M = 4;

    if (M > 0) {
        int* partial = (int*)d_ws;
        u64* pack = (u64*)((char*)d_ws + (size_t)M * N_ENTITIES * 4);
        int CH = N_TRIPLES / M;
        find_seg_kernel<<<K_SEG * M, 256, 0, stream>>>(h_idx, partial, M, CH);
        merge_join_kernel<<<(N_ENTITIES + 255) / 256, 256, 0, stream>>>(
            partial, r_idx, t_idx, pack, M);
        apply_kernel<<<N_ENTITIES / BLOCK_ROWS, 256, 0, stream>>>(
            memory, rel_table, pack, out);
    } else {
        u64* pack = (u64*)d_ws;                              // needs 4 MB
        {
            int n2 = N_ENTITIES / 2;
            init_pack_kernel<<<(n2 + 255) / 256, 256, 0, stream>>>(
                (ulonglong2*)pack, n2);
        }
        find_winner_kernel<<<(N_TRIPLES / 4 + 255) / 256, 256, 0, stream>>>(
            (const int4*)h_idx, (const int4*)r_idx, (const int4*)t_idx, pack);
        apply_kernel<<<N_ENTITIES / BLOCK_ROWS, 256, 0, stream>>>(
            memory, rel_table, pack, out);
    }
}